// Round 1
// baseline (620.123 us; speedup 1.0000x reference)
//
#include <hip/hip_runtime.h>
#include <math.h>

#define WUS   1028      // padded row stride for wu (1026 cols used)
#define NI    256
#define NO    256
#define KTOT  1026
#define SLEN  512
#define BB    8

// ---------------------------------------------------------------------------
// Kernel 1: wu[s][b][k] = dot(x[s][b][:], slow_W[k][:]) + slow_b[k]
// grid (512, 5), block 256. Block = 8 consecutive (s,b) rows x 256 k's.
// x rows are wave-uniform -> scalar loads; W rows as float4 vector loads.
// ---------------------------------------------------------------------------
__global__ __launch_bounds__(256) void k_wu(const float* __restrict__ x,
                                            const float* __restrict__ sw,
                                            const float* __restrict__ sb,
                                            float* __restrict__ wu) {
    const int t  = threadIdx.x;
    const int k  = blockIdx.y * 256 + t;
    const int r0 = blockIdx.x * 8;
    if (k >= KTOT) return;
    const float4* wk = (const float4*)(sw + (size_t)k * NI);
    float acc[8] = {0,0,0,0,0,0,0,0};
    for (int c4 = 0; c4 < 64; ++c4) {
        const float4 wv = wk[c4];
#pragma unroll
        for (int r = 0; r < 8; ++r) {
            const float* xr = x + (size_t)(r0 + r) * NI + c4 * 4;
            acc[r] = fmaf(wv.x, xr[0], acc[r]);
            acc[r] = fmaf(wv.y, xr[1], acc[r]);
            acc[r] = fmaf(wv.z, xr[2], acc[r]);
            acc[r] = fmaf(wv.w, xr[3], acc[r]);
        }
    }
    const float bk = sb[k];
#pragma unroll
    for (int r = 0; r < 8; ++r) wu[(size_t)(r0 + r) * WUS + k] = acc[r] + bk;
}

// ---------------------------------------------------------------------------
// Kernel 2: pack per-(o-pair, step) uniform records of 48 floats:
//   e in [0,16):  a1[bp][o2] = wu[j][bp][op*2+o2]        (bp=e>>1, o2=e&1)
//   e in [16,32): s1[bp][o2] = wu[j][bp][512+op*2+o2]
//   e in [32,40): sa[b] = sigmoid(wu[j][b][1024])
//   e in [40,48): ss[b] = sigmoid(wu[j][b][1025])
// rec index: (op*512 + j)*48 + e   -> consecutive j contiguous (K$ friendly)
// ---------------------------------------------------------------------------
__global__ __launch_bounds__(256) void k_rec(const float* __restrict__ wu,
                                             float* __restrict__ rec) {
    const int j = blockIdx.x;
    const int t = threadIdx.x;
    for (int f = t; f < 128 * 48; f += 256) {
        const int op = f / 48, e = f % 48;
        float v;
        if (e < 16) {
            v = wu[(size_t)(j * 8 + (e >> 1)) * WUS + (op * 2 + (e & 1))];
        } else if (e < 32) {
            const int e2 = e - 16;
            v = wu[(size_t)(j * 8 + (e2 >> 1)) * WUS + 512 + (op * 2 + (e2 & 1))];
        } else if (e < 40) {
            const float z = wu[(size_t)(j * 8 + (e - 32)) * WUS + 1024];
            v = 1.0f / (1.0f + expf(-z));
        } else {
            const float z = wu[(size_t)(j * 8 + (e - 40)) * WUS + 1025];
            v = 1.0f / (1.0f + expf(-z));
        }
        rec[((size_t)op * SLEN + j) * 48 + e] = v;
    }
}

// ---------------------------------------------------------------------------
// Kernel 3: the scan. 1024 independent waves; task = (b, o-pair).
// Lane l owns input columns [4l, 4l+4); keeps fw slice in registers.
// No barriers. Global float4 loads + uniform record prefetched 1 step ahead.
// ---------------------------------------------------------------------------
__global__ __launch_bounds__(256) void k_scan(const float* __restrict__ x,
                                              const float* __restrict__ w0,
                                              const float* __restrict__ wu,
                                              const float* __restrict__ rec,
                                              float* __restrict__ out) {
    const int t = threadIdx.x;
    const int l = t & 63;
    const int task = __builtin_amdgcn_readfirstlane((int)blockIdx.x * 4 + (t >> 6));
    const int b  = task >> 7;    // 0..7   (4 waves of a block share b)
    const int op = task & 127;   // 0..127 (o-pair)
    const int col = 4 * l;

    float fw0[4] = {0,0,0,0}, fw1[4] = {0,0,0,0};
    float w00[4], w01[4];
    {
        const float4 v0 = *(const float4*)(w0 + (size_t)(op * 2 + 0) * NI + col);
        const float4 v1 = *(const float4*)(w0 + (size_t)(op * 2 + 1) * NI + col);
        w00[0]=v0.x; w00[1]=v0.y; w00[2]=v0.z; w00[3]=v0.w;
        w01[0]=v1.x; w01[1]=v1.y; w01[2]=v1.z; w01[3]=v1.w;
    }

    const float* recs = rec + (size_t)op * (SLEN * 48);

    // ---- prefetch step 0 ----
    float4 a2c[8], s2c[8], xc;
    float a1c[16], s1c[16], sac, ssc;
#pragma unroll
    for (int bp = 0; bp < 8; ++bp) {
        a2c[bp] = *(const float4*)(wu + (size_t)bp * WUS + 256 + col);
        s2c[bp] = *(const float4*)(wu + (size_t)bp * WUS + 768 + col);
    }
    xc = *(const float4*)(x + (size_t)b * NI + col);
#pragma unroll
    for (int e = 0; e < 16; ++e) { a1c[e] = recs[e]; s1c[e] = recs[16 + e]; }
    sac = recs[32 + b]; ssc = recs[40 + b];

    for (int j = 0; j < SLEN; ++j) {
        // ---- issue prefetch for j+1 (clamped) ----
        const int jn = (j < SLEN - 1) ? j + 1 : SLEN - 1;
        float4 a2n[8], s2n[8], xn;
#pragma unroll
        for (int bp = 0; bp < 8; ++bp) {
            a2n[bp] = *(const float4*)(wu + (size_t)(jn * 8 + bp) * WUS + 256 + col);
            s2n[bp] = *(const float4*)(wu + (size_t)(jn * 8 + bp) * WUS + 768 + col);
        }
        xn = *(const float4*)(x + ((size_t)jn * 8 + b) * NI + col);
        const float* rjn = recs + (size_t)jn * 48;
        float a1n[16], s1n[16];
#pragma unroll
        for (int e = 0; e < 16; ++e) { a1n[e] = rjn[e]; s1n[e] = rjn[16 + e]; }
        const float san = rjn[32 + b], ssn = rjn[40 + b];

        // ---- compute step j ----
        float ad0[4]={0,0,0,0}, ad1[4]={0,0,0,0};
        float su0[4]={0,0,0,0}, su1[4]={0,0,0,0};
#pragma unroll
        for (int bp = 0; bp < 8; ++bp) {
            const float4 a2 = a2c[bp], s2 = s2c[bp];
            const float A0 = a1c[bp*2+0], A1 = a1c[bp*2+1];
            const float S0 = s1c[bp*2+0], S1 = s1c[bp*2+1];
            ad0[0]=fmaf(A0,a2.x,ad0[0]); ad0[1]=fmaf(A0,a2.y,ad0[1]);
            ad0[2]=fmaf(A0,a2.z,ad0[2]); ad0[3]=fmaf(A0,a2.w,ad0[3]);
            ad1[0]=fmaf(A1,a2.x,ad1[0]); ad1[1]=fmaf(A1,a2.y,ad1[1]);
            ad1[2]=fmaf(A1,a2.z,ad1[2]); ad1[3]=fmaf(A1,a2.w,ad1[3]);
            su0[0]=fmaf(S0,s2.x,su0[0]); su0[1]=fmaf(S0,s2.y,su0[1]);
            su0[2]=fmaf(S0,s2.z,su0[2]); su0[3]=fmaf(S0,s2.w,su0[3]);
            su1[0]=fmaf(S1,s2.x,su1[0]); su1[1]=fmaf(S1,s2.y,su1[1]);
            su1[2]=fmaf(S1,s2.z,su1[2]); su1[3]=fmaf(S1,s2.w,su1[3]);
        }
        float p0 = 0.0f, p1 = 0.0f;
        const float xv[4] = {xc.x, xc.y, xc.z, xc.w};
#pragma unroll
        for (int i = 0; i < 4; ++i) {
            fw0[i] = fmaf(sac, ad0[i], fmaf(-ssc, su0[i], fw0[i]));
            fw1[i] = fmaf(sac, ad1[i], fmaf(-ssc, su1[i], fw1[i]));
            p0 = fmaf(w00[i] + fw0[i], xv[i], p0);
            p1 = fmaf(w01[i] + fw1[i], xv[i], p1);
        }
        // ---- wave reduction over 64 lanes (sum over all 256 'in') ----
#pragma unroll
        for (int m = 1; m < 64; m <<= 1) {
            p0 += __shfl_xor(p0, m, 64);
            p1 += __shfl_xor(p1, m, 64);
        }
        if (l == 0) {
            float2 r; r.x = p0; r.y = p1;
            *(float2*)(out + ((size_t)j * 8 + b) * NO + op * 2) = r;
        }
        // ---- rotate prefetch buffers ----
#pragma unroll
        for (int bp = 0; bp < 8; ++bp) { a2c[bp] = a2n[bp]; s2c[bp] = s2n[bp]; }
        xc = xn;
#pragma unroll
        for (int e = 0; e < 16; ++e) { a1c[e] = a1n[e]; s1c[e] = s1n[e]; }
        sac = san; ssc = ssn;
    }
}

// ---------------------------------------------------------------------------
extern "C" void kernel_launch(void* const* d_in, const int* in_sizes, int n_in,
                              void* d_out, int out_size, void* d_ws, size_t ws_size,
                              hipStream_t stream) {
    const float* x  = (const float*)d_in[0];   // (512, 8, 256)
    const float* sw = (const float*)d_in[1];   // (1026, 256)
    const float* sb = (const float*)d_in[2];   // (1026,)
    const float* w0 = (const float*)d_in[3];   // (256, 256)
    float* out = (float*)d_out;                // (512, 8, 256)

    float* wu  = (float*)d_ws;                       // 4096 * 1028 floats
    float* rec = wu + (size_t)4096 * WUS;            // 128 * 512 * 48 floats

    dim3 g1(512, 5);
    k_wu<<<g1, 256, 0, stream>>>(x, sw, sb, wu);
    k_rec<<<SLEN, 256, 0, stream>>>(wu, rec);
    k_scan<<<256, 256, 0, stream>>>(x, w0, wu, rec, out);
}

// Round 2
// 267.077 us; speedup vs baseline: 2.3219x; 2.3219x over previous
//
#include <hip/hip_runtime.h>
#include <math.h>

typedef __bf16 bf16;
typedef __attribute__((ext_vector_type(8))) __bf16 bf16x8;
typedef __attribute__((ext_vector_type(4))) float f32x4;

#define MFMA16(a, b, c) __builtin_amdgcn_mfma_f32_16x16x32_bf16(a, b, c, 0, 0, 0)

#define NI 256
#define SLEN 512
#define NTQ 4096          // 512*8 flattened (j,b)
#define SEGT 9            // TK tiles per segment block

// ---------------------------------------------------------------------------
// k_prep: wu GEMM (fp32) -> bf16 operand arrays + fp32 gates + bf16 X copy.
//   y=0: A1T[o][jb]   (transposed, bf16)   from wu cols [0,256)
//   y=1: A2g[jb][i]   (row-major, bf16)    from wu cols [256,512)
//   y=2: S1T[o][jb]   (transposed, bf16)   from wu cols [512,768)
//   y=3: S2g[jb][i]   (row-major, bf16)    from wu cols [768,1024)
//   y=4: sag/ssg[jb]  (fp32 sigmoid)       from wu cols 1024/1025
// ---------------------------------------------------------------------------
__global__ __launch_bounds__(256) void k_prep(const float* __restrict__ x,
                                              const float* __restrict__ sw,
                                              const float* __restrict__ sb,
                                              bf16* __restrict__ A1T,
                                              bf16* __restrict__ S1T,
                                              bf16* __restrict__ A2g,
                                              bf16* __restrict__ S2g,
                                              bf16* __restrict__ Xg,
                                              float* __restrict__ sag,
                                              float* __restrict__ ssg) {
    const int t  = threadIdx.x;
    const int y  = blockIdx.y;
    const int r0 = blockIdx.x * 8;

    if (y == 4) {
        if (t < 16) {
            const int kk = t & 1;   // 0 -> sa, 1 -> ss
            const int r  = t >> 1;  // row 0..7
            const float* wk = sw + (size_t)(1024 + kk) * NI;
            const float* xr = x + (size_t)(r0 + r) * NI;
            float a = 0.f;
            for (int i = 0; i < NI; ++i) a = fmaf(wk[i], xr[i], a);
            const float z = a + sb[1024 + kk];
            const float s = 1.0f / (1.0f + expf(-z));
            (kk == 0 ? sag : ssg)[r0 + r] = s;
        }
        return;
    }

    const int k = y * 256 + t;
    const float4* wk = (const float4*)(sw + (size_t)k * NI);
    float acc[8] = {0, 0, 0, 0, 0, 0, 0, 0};
    for (int c4 = 0; c4 < 64; ++c4) {
        const float4 wv = wk[c4];
#pragma unroll
        for (int r = 0; r < 8; ++r) {
            const float* xr = x + (size_t)(r0 + r) * NI + c4 * 4;
            acc[r] = fmaf(wv.x, xr[0], acc[r]);
            acc[r] = fmaf(wv.y, xr[1], acc[r]);
            acc[r] = fmaf(wv.z, xr[2], acc[r]);
            acc[r] = fmaf(wv.w, xr[3], acc[r]);
        }
    }
    const float bk = sb[k];

    if (y == 0 || y == 2) {
        bf16x8 pk;
#pragma unroll
        for (int r = 0; r < 8; ++r) pk[r] = (bf16)(acc[r] + bk);
        bf16* dst = (y == 0 ? A1T : S1T) + (size_t)t * NTQ + r0;
        *(bf16x8*)dst = pk;
        if (y == 0) {
#pragma unroll
            for (int r = 0; r < 8; ++r)
                Xg[(size_t)(r0 + r) * NI + t] = (bf16)x[(size_t)(r0 + r) * NI + t];
        }
    } else {
        bf16* dst = (y == 1 ? A2g : S2g);
#pragma unroll
        for (int r = 0; r < 8; ++r)
            dst[(size_t)(r0 + r) * NI + t] = (bf16)(acc[r] + bk);
    }
}

// ---------------------------------------------------------------------------
// k_base: out[jb][o] = sum_i W0[o][i] * x[jb][i]   (fp32 exact; initializes
// d_out, k_attn atomically accumulates on top)
// ---------------------------------------------------------------------------
__global__ __launch_bounds__(256) void k_base(const float* __restrict__ x,
                                              const float* __restrict__ w0,
                                              float* __restrict__ out) {
    const int t  = threadIdx.x;      // o
    const int r0 = blockIdx.x * 8;
    const float4* wk = (const float4*)(w0 + (size_t)t * NI);
    float acc[8] = {0, 0, 0, 0, 0, 0, 0, 0};
    for (int c4 = 0; c4 < 64; ++c4) {
        const float4 wv = wk[c4];
#pragma unroll
        for (int r = 0; r < 8; ++r) {
            const float* xr = x + (size_t)(r0 + r) * NI + c4 * 4;
            acc[r] = fmaf(wv.x, xr[0], acc[r]);
            acc[r] = fmaf(wv.y, xr[1], acc[r]);
            acc[r] = fmaf(wv.z, xr[2], acc[r]);
            acc[r] = fmaf(wv.w, xr[3], acc[r]);
        }
    }
#pragma unroll
    for (int r = 0; r < 8; ++r) out[(size_t)(r0 + r) * NI + t] = acc[r];
}

// ---------------------------------------------------------------------------
// k_attn: blockwise-causal linear attention.
// Block = (q TQ-tile of 64 rows, seg of <=9 TK-tiles). 8 waves (512 thr).
// Per TK-tile (64 TK = 8 steps):
//   S[64x128] = X_tile . [A2|S2]_tile^T  (MFMA, K=256)
//   P = gate-scale(+mask on diagonal), bf16 -> LDS
//   outacc[64x256] += P . [A1;S1]_tile   (MFMA, K'=128)
// Block end: atomicAdd into d_out (pre-filled with base by k_base).
// ---------------------------------------------------------------------------
__global__ __launch_bounds__(512) void k_attn(const bf16* __restrict__ A2g,
                                              const bf16* __restrict__ S2g,
                                              const bf16* __restrict__ A1T,
                                              const bf16* __restrict__ S1T,
                                              const bf16* __restrict__ Xg,
                                              const float* __restrict__ sag,
                                              const float* __restrict__ ssg,
                                              float* __restrict__ out) {
    const int q   = blockIdx.x;       // TQ tile index (0..63)
    const int seg = blockIdx.y;       // TK segment (0..7)
    int kt = seg * SEGT;
    const int ktEnd = min(kt + SEGT, q + 1);
    if (kt >= ktEnd) return;

    const int tid = threadIdx.x;
    const int l   = tid & 63;
    const int w   = tid >> 6;
    const int mw  = w >> 2;           // 0..1 : 32-row half
    const int nw  = w & 3;            // 0..3 : N-group
    const int lr  = l & 15;
    const int lc  = l >> 4;
    const int tq0 = q * 64;

    __shared__ __align__(16) bf16 Pl[64][136];
    __shared__ float ga[64], gs[64];

    // persistent X A-fragments: rows mw*32+mi*16+lr, k = kk*32+lc*8..+8
    bf16x8 xa[2][8];
#pragma unroll
    for (int mi = 0; mi < 2; ++mi)
#pragma unroll
        for (int kk = 0; kk < 8; ++kk)
            xa[mi][kk] = *(const bf16x8*)(Xg + (size_t)(tq0 + mw * 32 + mi * 16 + lr) * NI +
                                          kk * 32 + lc * 8);

    f32x4 acco[2][4];
#pragma unroll
    for (int mi = 0; mi < 2; ++mi)
#pragma unroll
        for (int ni = 0; ni < 4; ++ni) acco[mi][ni] = (f32x4){0.f, 0.f, 0.f, 0.f};

    const bf16* Bsrc  = (nw < 2) ? A2g : S2g;
    const int   ncol0 = (nw & 1) * 32;          // TK-local col base within part
    const int   pbase = (nw >> 1) * 64;         // 0 for a-part, 64 for s-part
    const float sgn   = (nw < 2) ? 1.f : -1.f;

    for (; kt < ktEnd; ++kt) {
        const int TK0 = kt * 64;
        // stage gates for this TK tile (sa/ss for steps kt*8..kt*8+7, all b)
        if (tid < 64) ga[tid] = sag[TK0 + tid];
        else if (tid < 128) gs[tid - 64] = ssg[TK0 + tid - 128 + 64];

        // ---- S phase: S[m=TQ][n=TK] = sum_i X[m][i] * Bsrc[n][i] ----
        f32x4 accs[2][2];
#pragma unroll
        for (int mi = 0; mi < 2; ++mi)
#pragma unroll
            for (int ni = 0; ni < 2; ++ni) accs[mi][ni] = (f32x4){0.f, 0.f, 0.f, 0.f};
#pragma unroll
        for (int kk = 0; kk < 8; ++kk) {
#pragma unroll
            for (int ni = 0; ni < 2; ++ni) {
                const bf16x8 bfg = *(const bf16x8*)(Bsrc +
                    (size_t)(TK0 + ncol0 + ni * 16 + lr) * NI + kk * 32 + lc * 8);
#pragma unroll
                for (int mi = 0; mi < 2; ++mi)
                    accs[mi][ni] = MFMA16(xa[mi][kk], bfg, accs[mi][ni]);
            }
        }

        __syncthreads();   // prev out-phase done with Pl; gates visible

        // ---- P = gate * S (mask on diagonal tile), store bf16 to LDS ----
#pragma unroll
        for (int mi = 0; mi < 2; ++mi) {
#pragma unroll
            for (int ni = 0; ni < 2; ++ni) {
#pragma unroll
                for (int v = 0; v < 4; ++v) {
                    const int row = mw * 32 + mi * 16 + lc * 4 + v;  // TQ local
                    const int pcl = ncol0 + ni * 16 + lr;            // TK local
                    const float g = (nw < 2 ? ga : gs)[(pcl & 56) + (row & 7)];
                    float p = sgn * g * accs[mi][ni][v];
                    if (kt == q && (pcl >> 3) > (row >> 3)) p = 0.f;  // causal
                    Pl[row][pbase + pcl] = (bf16)p;
                }
            }
        }

        __syncthreads();   // P visible

        // ---- out phase: acco[m][n] += sum_k' P[m][k'] * B1[k'][n] ----
#pragma unroll
        for (int kk2 = 0; kk2 < 4; ++kk2) {
            const bf16* Tsrc = (kk2 < 2) ? A1T : S1T;
            const int kof = (kk2 & 1) * 32 + lc * 8;
            bf16x8 af[2];
#pragma unroll
            for (int mi = 0; mi < 2; ++mi)
                af[mi] = *(const bf16x8*)(&Pl[mw * 32 + mi * 16 + lr][kk2 * 32 + lc * 8]);
#pragma unroll
            for (int ni = 0; ni < 4; ++ni) {
                const bf16x8 bfg = *(const bf16x8*)(Tsrc +
                    (size_t)(nw * 64 + ni * 16 + lr) * NTQ + TK0 + kof);
#pragma unroll
                for (int mi = 0; mi < 2; ++mi)
                    acco[mi][ni] = MFMA16(af[mi], bfg, acco[mi][ni]);
            }
        }
    }

    // ---- accumulate into d_out ----
#pragma unroll
    for (int mi = 0; mi < 2; ++mi)
#pragma unroll
        for (int ni = 0; ni < 4; ++ni)
#pragma unroll
            for (int v = 0; v < 4; ++v)
                atomicAdd(out + (size_t)(tq0 + mw * 32 + mi * 16 + lc * 4 + v) * 256 +
                              nw * 64 + ni * 16 + lr,
                          acco[mi][ni][v]);
}

// ---------------------------------------------------------------------------
extern "C" void kernel_launch(void* const* d_in, const int* in_sizes, int n_in,
                              void* d_out, int out_size, void* d_ws, size_t ws_size,
                              hipStream_t stream) {
    const float* x  = (const float*)d_in[0];   // (512, 8, 256)
    const float* sw = (const float*)d_in[1];   // (1026, 256)
    const float* sb = (const float*)d_in[2];   // (1026,)
    const float* w0 = (const float*)d_in[3];   // (256, 256)
    float* out = (float*)d_out;                // (512, 8, 256)

    const size_t N1 = (size_t)256 * NTQ;       // 1,048,576 elements
    bf16* A1T = (bf16*)d_ws;
    bf16* S1T = A1T + N1;
    bf16* A2g = S1T + N1;
    bf16* S2g = A2g + N1;
    bf16* Xg  = S2g + N1;
    float* sag = (float*)(Xg + N1);
    float* ssg = sag + NTQ;

    dim3 gp(512, 5);
    k_prep<<<gp, 256, 0, stream>>>(x, sw, sb, A1T, S1T, A2g, S2g, Xg, sag, ssg);
    k_base<<<512, 256, 0, stream>>>(x, w0, out);
    dim3 ga(64, 8);
    k_attn<<<ga, 512, 0, stream>>>(A2g, S2g, A1T, S1T, Xg, sag, ssg, out);
}

// Round 3
// 186.995 us; speedup vs baseline: 3.3163x; 1.4283x over previous
//
#include <hip/hip_runtime.h>
#include <math.h>

typedef __bf16 bf16;
typedef __attribute__((ext_vector_type(8))) __bf16 bf16x8;
typedef __attribute__((ext_vector_type(4))) float f32x4;

#define MFMA16(a, b, c) __builtin_amdgcn_mfma_f32_16x16x32_bf16(a, b, c, 0, 0, 0)

#define NI 256
#define NTQ 4096

// ---------------------------------------------------------------------------
// k_prep: wu GEMM (fp32) -> bf16 operands + fp32 gates + bf16 X copy.
//   y=0: A1B[kt][o][k']  tile-packed (kt = jb>>6, k' = jb&63)   cols [0,256)
//   y=1: A2g[jb][i]      row-major                              cols [256,512)
//   y=2: S1B[kt][o][k']  tile-packed                            cols [512,768)
//   y=3: S2g[jb][i]      row-major                              cols [768,1024)
//   y=4: sag/ssg[jb]     fp32 sigmoid                           cols 1024/1025
// ---------------------------------------------------------------------------
__global__ __launch_bounds__(256) void k_prep(const float* __restrict__ x,
                                              const float* __restrict__ sw,
                                              const float* __restrict__ sb,
                                              bf16* __restrict__ A1B,
                                              bf16* __restrict__ S1B,
                                              bf16* __restrict__ A2g,
                                              bf16* __restrict__ S2g,
                                              bf16* __restrict__ Xg,
                                              float* __restrict__ sag,
                                              float* __restrict__ ssg) {
    const int t  = threadIdx.x;
    const int y  = blockIdx.y;
    const int r0 = blockIdx.x * 8;

    if (y == 4) {
        if (t < 16) {
            const int kk = t & 1;
            const int r  = t >> 1;
            const float* wk = sw + (size_t)(1024 + kk) * NI;
            const float* xr = x + (size_t)(r0 + r) * NI;
            float a = 0.f;
            for (int i = 0; i < NI; ++i) a = fmaf(wk[i], xr[i], a);
            const float z = a + sb[1024 + kk];
            (kk == 0 ? sag : ssg)[r0 + r] = 1.0f / (1.0f + expf(-z));
        }
        return;
    }

    const int k = y * 256 + t;
    const float4* wk = (const float4*)(sw + (size_t)k * NI);
    float acc[8] = {0, 0, 0, 0, 0, 0, 0, 0};
    for (int c4 = 0; c4 < 64; ++c4) {
        const float4 wv = wk[c4];
#pragma unroll
        for (int r = 0; r < 8; ++r) {
            const float* xr = x + (size_t)(r0 + r) * NI + c4 * 4;
            acc[r] = fmaf(wv.x, xr[0], acc[r]);
            acc[r] = fmaf(wv.y, xr[1], acc[r]);
            acc[r] = fmaf(wv.z, xr[2], acc[r]);
            acc[r] = fmaf(wv.w, xr[3], acc[r]);
        }
    }
    const float bk = sb[k];

    if (y == 0 || y == 2) {
        bf16x8 pk;
#pragma unroll
        for (int r = 0; r < 8; ++r) pk[r] = (bf16)(acc[r] + bk);
        // tile-packed: [kt=r0>>6][o=t][k'=r0&63 .. +8]
        bf16* dst = (y == 0 ? A1B : S1B) +
                    ((size_t)(r0 >> 6)) * 16384 + (size_t)t * 64 + (r0 & 63);
        *(bf16x8*)dst = pk;
        if (y == 0) {
#pragma unroll
            for (int r = 0; r < 8; ++r)
                Xg[(size_t)(r0 + r) * NI + t] = (bf16)x[(size_t)(r0 + r) * NI + t];
        }
    } else {
        bf16* dst = (y == 1 ? A2g : S2g);
#pragma unroll
        for (int r = 0; r < 8; ++r)
            dst[(size_t)(r0 + r) * NI + t] = (bf16)(acc[r] + bk);
    }
}

// ---------------------------------------------------------------------------
// k_base: out[jb][o] = sum_i W0[o][i] * x[jb][i]   (fp32 exact)
// ---------------------------------------------------------------------------
__global__ __launch_bounds__(256) void k_base(const float* __restrict__ x,
                                              const float* __restrict__ w0,
                                              float* __restrict__ out) {
    const int t  = threadIdx.x;
    const int r0 = blockIdx.x * 8;
    const float4* wk = (const float4*)(w0 + (size_t)t * NI);
    float acc[8] = {0, 0, 0, 0, 0, 0, 0, 0};
    for (int c4 = 0; c4 < 64; ++c4) {
        const float4 wv = wk[c4];
#pragma unroll
        for (int r = 0; r < 8; ++r) {
            const float* xr = x + (size_t)(r0 + r) * NI + c4 * 4;
            acc[r] = fmaf(wv.x, xr[0], acc[r]);
            acc[r] = fmaf(wv.y, xr[1], acc[r]);
            acc[r] = fmaf(wv.z, xr[2], acc[r]);
            acc[r] = fmaf(wv.w, xr[3], acc[r]);
        }
    }
#pragma unroll
    for (int r = 0; r < 8; ++r) out[(size_t)(r0 + r) * NI + t] = acc[r];
}

// ---------------------------------------------------------------------------
// k_attn: blockwise-causal linear attention, zero-redundancy decomposition.
// Block = (q-tile 64 rows, seg of <=SEGT TK-tiles), 8 waves.
//   wave w: ih=w>>2 (i-half for S-phase), sub=w&3 (32 score-cols)
//   S-phase: accs over i-half; ih0 stores partial to PT (f32, transposed),
//            ih1 merges + gate-scales + masks -> PB (bf16)
//   out-phase: wave w owns o-cols [w*32,w*32+32), K'=128 full, acco persists.
// Partials to part[seg] (no atomics); k_reduce sums valid segs into out.
// ---------------------------------------------------------------------------
__global__ __launch_bounds__(512, 2) void k_attn(const bf16* __restrict__ A2g,
                                                 const bf16* __restrict__ S2g,
                                                 const bf16* __restrict__ A1B,
                                                 const bf16* __restrict__ S1B,
                                                 const bf16* __restrict__ Xg,
                                                 const float* __restrict__ sag,
                                                 const float* __restrict__ ssg,
                                                 float* __restrict__ part,
                                                 int SEGT) {
    const int q   = blockIdx.x;
    const int seg = blockIdx.y;
    int kt = seg * SEGT;
    const int ktEnd = min(kt + SEGT, q + 1);
    if (kt >= ktEnd) return;

    const int tid = threadIdx.x;
    const int l   = tid & 63;
    const int w   = tid >> 6;
    const int lr  = l & 15;
    const int lc  = l >> 4;
    const int ih  = w >> 2;
    const int sub = w & 3;
    const int tq0 = q * 64;

    __shared__ __align__(16) float PT[128][68];   // [score-col][m] transposed
    __shared__ __align__(16) bf16  PB[64][136];   // [m][score-col] bf16
    __shared__ float ga[64], gs[64];

    // persistent X fragments for this wave's i-half: rows tq0+mi*16+lr,
    // i = ih*128 + kk*32 + lc*8
    bf16x8 xa[4][4];
#pragma unroll
    for (int mi = 0; mi < 4; ++mi)
#pragma unroll
        for (int kk = 0; kk < 4; ++kk)
            xa[mi][kk] = *(const bf16x8*)(Xg + (size_t)(tq0 + mi * 16 + lr) * NI +
                                          ih * 128 + kk * 32 + lc * 8);

    f32x4 acco[4][2];
#pragma unroll
    for (int mi = 0; mi < 4; ++mi)
#pragma unroll
        for (int ni = 0; ni < 2; ++ni) acco[mi][ni] = (f32x4){0.f, 0.f, 0.f, 0.f};

    const bf16* Bsrc = (sub < 2) ? A2g : S2g;
    const float sgn  = (sub < 2) ? 1.f : -1.f;

    for (; kt < ktEnd; ++kt) {
        const int TK0 = kt * 64;
        if (tid < 64) ga[tid] = sag[TK0 + tid];
        else if (tid < 128) gs[tid - 64] = ssg[TK0 + tid - 64];

        // ---- S phase (this wave's i-half) ----
        f32x4 accs[4][2];
#pragma unroll
        for (int mi = 0; mi < 4; ++mi)
#pragma unroll
            for (int ni = 0; ni < 2; ++ni) accs[mi][ni] = (f32x4){0.f, 0.f, 0.f, 0.f};
#pragma unroll
        for (int kk = 0; kk < 4; ++kk) {
#pragma unroll
            for (int ni = 0; ni < 2; ++ni) {
                const bf16x8 bfg = *(const bf16x8*)(Bsrc +
                    (size_t)(TK0 + (sub & 1) * 32 + ni * 16 + lr) * NI +
                    ih * 128 + kk * 32 + lc * 8);
#pragma unroll
                for (int mi = 0; mi < 4; ++mi)
                    accs[mi][ni] = MFMA16(xa[mi][kk], bfg, accs[mi][ni]);
            }
        }

        if (ih == 0) {
#pragma unroll
            for (int mi = 0; mi < 4; ++mi)
#pragma unroll
                for (int ni = 0; ni < 2; ++ni)
                    *(f32x4*)&PT[sub * 32 + ni * 16 + lr][mi * 16 + lc * 4] = accs[mi][ni];
        }
        __syncthreads();   // B1: PT visible; gates visible

        if (ih == 1) {
#pragma unroll
            for (int mi = 0; mi < 4; ++mi) {
#pragma unroll
                for (int ni = 0; ni < 2; ++ni) {
                    const int cL  = sub * 32 + ni * 16 + lr;   // 0..127
                    const int tkL = cL & 63;
                    const f32x4 o = *(const f32x4*)&PT[cL][mi * 16 + lc * 4];
#pragma unroll
                    for (int v = 0; v < 4; ++v) {
                        const int row = mi * 16 + lc * 4 + v;
                        const float g = (sub < 2 ? ga : gs)[(tkL & 56) + (row & 7)];
                        float p = sgn * g * (accs[mi][ni][v] + o[v]);
                        const int ks = kt * 8 + (tkL >> 3);
                        const int js = q * 8 + (row >> 3);
                        if (ks > js) p = 0.f;                  // causal
                        PB[row][cL] = (bf16)p;
                    }
                }
            }
        }
        __syncthreads();   // B2: PB visible

        // ---- out phase: o-cols [w*32, w*32+32), K' = 128 ----
#pragma unroll
        for (int kk2 = 0; kk2 < 4; ++kk2) {
            const bf16* Tsrc = (kk2 < 2) ? A1B : S1B;
            bf16x8 af[4];
#pragma unroll
            for (int mi = 0; mi < 4; ++mi)
                af[mi] = *(const bf16x8*)&PB[mi * 16 + lr][kk2 * 32 + lc * 8];
#pragma unroll
            for (int nio = 0; nio < 2; ++nio) {
                const bf16x8 bfg = *(const bf16x8*)(Tsrc + (size_t)kt * 16384 +
                    (size_t)(w * 32 + nio * 16 + lr) * 64 + (kk2 & 1) * 32 + lc * 8);
#pragma unroll
                for (int mi = 0; mi < 4; ++mi)
                    acco[mi][nio] = MFMA16(af[mi], bfg, acco[mi][nio]);
            }
        }
    }

    // ---- write per-segment partial (plain stores, no atomics) ----
    float* dst = part + (size_t)seg * ((size_t)NTQ * 256);
#pragma unroll
    for (int mi = 0; mi < 4; ++mi)
#pragma unroll
        for (int nio = 0; nio < 2; ++nio)
#pragma unroll
            for (int v = 0; v < 4; ++v)
                dst[(size_t)(tq0 + mi * 16 + lc * 4 + v) * 256 + w * 32 + nio * 16 + lr] =
                    acco[mi][nio][v];
}

// ---------------------------------------------------------------------------
// k_reduce: out += sum over valid segments of part
// ---------------------------------------------------------------------------
__global__ __launch_bounds__(256) void k_reduce(const float* __restrict__ part,
                                                float* __restrict__ out,
                                                int SEGT, int nseg) {
    const int idx = blockIdx.x * 256 + threadIdx.x;   // f32x4 index, 262144 total
    const int jb  = idx >> 6;
    const int q   = jb >> 6;
    int ns = (q + SEGT) / SEGT;    // ceil((q+1)/SEGT)
    if (ns > nseg) ns = nseg;
    f32x4 acc = *((const f32x4*)out + idx);
    for (int s = 0; s < ns; ++s)
        acc += *((const f32x4*)part + (size_t)s * 262144 + idx);
    *((f32x4*)out + idx) = acc;
}

// ---------------------------------------------------------------------------
extern "C" void kernel_launch(void* const* d_in, const int* in_sizes, int n_in,
                              void* d_out, int out_size, void* d_ws, size_t ws_size,
                              hipStream_t stream) {
    const float* x  = (const float*)d_in[0];
    const float* sw = (const float*)d_in[1];
    const float* sb = (const float*)d_in[2];
    const float* w0 = (const float*)d_in[3];
    float* out = (float*)d_out;

    const size_t N1 = (size_t)256 * NTQ;        // 1,048,576 elements
    bf16* A1B = (bf16*)d_ws;
    bf16* S1B = A1B + N1;
    bf16* A2g = S1B + N1;
    bf16* S2g = A2g + N1;
    bf16* Xg  = S2g + N1;
    float* sag = (float*)(Xg + N1);
    float* ssg = sag + NTQ;
    float* partb = ssg + NTQ;

    const size_t baseBytes = (size_t)((char*)partb - (char*)d_ws);
    int nseg = 1;
    if (ws_size > baseBytes + (4u << 20))
        nseg = (int)((ws_size - baseBytes) / ((size_t)NTQ * 256 * 4));
    if (nseg > 8) nseg = 8;
    if (nseg < 1) nseg = 1;
    const int SEGT = (64 + nseg - 1) / nseg;

    dim3 gp(512, 5);
    k_prep<<<gp, 256, 0, stream>>>(x, sw, sb, A1B, S1B, A2g, S2g, Xg, sag, ssg);
    k_base<<<512, 256, 0, stream>>>(x, w0, out);
    dim3 ga(64, nseg);
    k_attn<<<ga, 512, 0, stream>>>(A2g, S2g, A1B, S1B, Xg, sag, ssg, partb, SEGT);
    k_reduce<<<1024, 256, 0, stream>>>(partb, out, SEGT, nseg);
}